// Round 1
// baseline (174.061 us; speedup 1.0000x reference)
//
#include <hip/hip_runtime.h>
#include <stdint.h>

typedef unsigned long long u64;

#define NNODE 4096
#define NG    8
#define M     512      // nodes per graph
#define W     8        // 64-bit words per 512-bit mask

// workspace layout (bytes)
#define OFF_MASK 0                         // u64[4096][8]     = 262144 B
#define OFF_DEG  (262144)                  // float[4096]      =  16384 B
#define OFF_F1   (262144 + 16384)          // float[4096]      =  16384 B
#define OFF_FEAT (262144 + 32768)          // float[8][7][512] = 114688 B
// total 409600 B

// ---------------------------------------------------------------------------
// Kernel 1: pack diagonal-block adjacency rows into 512-bit masks + degrees.
// One wave per row; lane l covers columns [8l, 8l+8) of the block.
// ---------------------------------------------------------------------------
__global__ __launch_bounds__(256) void k_pack(const float* __restrict__ A,
                                              u64* __restrict__ gmask,
                                              float* __restrict__ gdeg) {
    int row  = (blockIdx.x << 2) + (threadIdx.x >> 6);  // 0..4095
    int lane = threadIdx.x & 63;
    int lo   = (row >> 9) << 9;                         // block column base
    const float* rowp = A + (size_t)row * NNODE + lo;
    float4 a = *(const float4*)(rowp + lane * 8);
    float4 b = *(const float4*)(rowp + lane * 8 + 4);
    unsigned int byte =
        (a.x != 0.f ? 1u : 0u) | (a.y != 0.f ? 2u : 0u) |
        (a.z != 0.f ? 4u : 0u) | (a.w != 0.f ? 8u : 0u) |
        (b.x != 0.f ? 16u : 0u) | (b.y != 0.f ? 32u : 0u) |
        (b.z != 0.f ? 64u : 0u) | (b.w != 0.f ? 128u : 0u);
    ((unsigned char*)gmask)[(size_t)row * 64 + lane] = (unsigned char)byte;
    int c = __popc(byte);
#pragma unroll
    for (int off = 32; off; off >>= 1) c += __shfl_down(c, off, 64);
    if (lane == 0) gdeg[row] = (float)c;
}

// ---------------------------------------------------------------------------
// Kernel 2: pairwise popcount features. Block = (graph g, 64-node chunk).
// 4 waves; wave w scans v-range [128w,128w+128); lane = node within chunk.
// mask[v] LDS reads are wave-uniform => broadcast, conflict-free.
// ---------------------------------------------------------------------------
__global__ __launch_bounds__(256) void k_pair(const u64* __restrict__ gmask,
                                              const float* __restrict__ gdeg,
                                              float* __restrict__ featg,
                                              float* __restrict__ f1g) {
    int g     = blockIdx.x >> 3;
    int chunk = blockIdx.x & 7;
    int t     = threadIdx.x;
    int wv    = t >> 6, lane = t & 63;

    __shared__ __align__(16) u64 smask[M * W];   // 32 KB
    __shared__ float sdeg[M];
    __shared__ float pf5[256], pf2[256];
    __shared__ int   pf4[256], pf6[256];

    const u64* gm = gmask + (size_t)g * M * W;
#pragma unroll
    for (int k = 0; k < 16; k++) smask[k * 256 + t] = gm[k * 256 + t];
    sdeg[t]       = gdeg[g * M + t];
    sdeg[t + 256] = gdeg[g * M + t + 256];
    __syncthreads();

    int n = chunk * 64 + lane;
    u64 m1[W];
#pragma unroll
    for (int w = 0; w < W; w++) m1[w] = smask[n * W + w];
    m1[n >> 6] |= 1ull << (n & 63);              // M1 = A | I (ego incl. self)

    int f4 = 0, f6 = 0;
    float f5 = 0.f, f2 = 0.f;
    int v0 = wv * 128;
    for (int v = v0; v < v0 + 128; v++) {
        const u64* mv = &smask[v * W];
        int c = 0;
#pragma unroll
        for (int w = 0; w < W; w++) c += __popcll(m1[w] & mv[w]);
        int m1b = (int)((m1[v >> 6] >> (v & 63)) & 1ull);
        int m2  = m1b | (c > 0 ? 1 : 0);
        float dv = sdeg[v];
        if (m1b) f4 += c;                        // (B*M1) row sum
        if (m2)  { f5 += dv; f6++; }             // M2@deg, |ego2|
        if (m1b && v != n) f2 += dv;             // A@deg (exclude self)
    }
    pf4[t] = f4; pf6[t] = f6; pf5[t] = f5; pf2[t] = f2;
    __syncthreads();

    if (t < 64) {
        int nn = chunk * 64 + t;
        float deg = sdeg[nn];
        int   f4i = pf4[t] + pf4[64 + t] + pf4[128 + t] + pf4[192 + t];
        int   f6c = pf6[t] + pf6[64 + t] + pf6[128 + t] + pf6[192 + t];
        float f5s = pf5[t] + pf5[64 + t] + pf5[128 + t] + pf5[192 + t];
        float f2s = pf2[t] + pf2[64 + t] + pf2[128 + t] + pf2[192 + t];
        float f4raw = (float)f4i;
        float f1 = (deg > 1.f) ? 2.f * (f4raw - deg) / (deg * (deg - 1.f)) : 0.f;
        float f2v = (deg > 0.f) ? f2s / deg : 0.f;
        float* fb = featg + (size_t)g * 7 * M;
        fb[0 * M + nn] = deg;
        fb[1 * M + nn] = f1;
        fb[2 * M + nn] = f2v;
        fb[4 * M + nn] = f4raw * 0.5f;
        fb[5 * M + nn] = f5s - 2.f * f4raw;
        fb[6 * M + nn] = (float)f6c - deg - 1.f;
        f1g[g * M + nn] = f1;
    }
}

// ---------------------------------------------------------------------------
// Kernel 3: f3 (neighbor mean of f1) + per-graph statistics. Block per graph.
// ---------------------------------------------------------------------------
__global__ __launch_bounds__(1024) void k_stats(const u64* __restrict__ gmask,
                                                const float* __restrict__ gdeg,
                                                const float* __restrict__ f1g,
                                                const float* __restrict__ featg,
                                                float* __restrict__ out) {
    int g = blockIdx.x;
    int t = threadIdx.x;
    __shared__ float sfeat[7 * M];   // [f][n]
    __shared__ float f1s[M];

    const float* fb = featg + (size_t)g * 7 * M;
    for (int idx = t; idx < 7 * M; idx += 1024) sfeat[idx] = fb[idx];
    if (t < M) f1s[t] = f1g[g * M + t];
    __syncthreads();

    if (t < M) {
        const u64* m = gmask + ((size_t)g * M + t) * W;
        float sum = 0.f;
#pragma unroll
        for (int w = 0; w < W; w++) {
            u64 bits = m[w];                     // A row (no self bit)
            while (bits) {
                int b = __ffsll(bits) - 1;
                sum += f1s[w * 64 + b];
                bits &= bits - 1;
            }
        }
        float deg = gdeg[g * M + t];
        sfeat[3 * M + t] = (deg > 0.f) ? sum / deg : 0.f;
    }
    __syncthreads();

    // --- median: rank-count selection, lower-middle element (rank 255) ---
    for (int T = t; T < 7 * M; T += 1024) {
        int f = T >> 9, i = T & (M - 1);
        float cv = sfeat[f * M + i];
        int less = 0, eq = 0;
        for (int j = 0; j < M; j++) {
            float x = sfeat[f * M + j];          // wave-uniform => LDS broadcast
            less += (x < cv);
            eq   += (x == cv);
        }
        if (less <= 255 && less + eq > 255) out[g * 35 + 7 + f] = cv;
    }

    // --- moments: wave f handles feature f (waves 0..6) ---
    int wv = t >> 6, lane = t & 63;
    if (wv < 7) {
        int f = wv;
        float vals[8];
        double s = 0.0;
#pragma unroll
        for (int k = 0; k < 8; k++) { vals[k] = sfeat[f * M + lane + 64 * k]; s += (double)vals[k]; }
#pragma unroll
        for (int off = 32; off; off >>= 1) s += __shfl_xor(s, off, 64);
        double mean = s * (1.0 / 512.0);
        double c2 = 0.0, c3 = 0.0, c4 = 0.0;
#pragma unroll
        for (int k = 0; k < 8; k++) {
            double c = (double)vals[k] - mean;
            double cc = c * c;
            c2 += cc; c3 += cc * c; c4 += cc * cc;
        }
#pragma unroll
        for (int off = 32; off; off >>= 1) {
            c2 += __shfl_xor(c2, off, 64);
            c3 += __shfl_xor(c3, off, 64);
            c4 += __shfl_xor(c4, off, 64);
        }
        if (lane == 0) {
            double m2 = c2 * (1.0 / 512.0);
            double m3 = c3 * (1.0 / 512.0);
            double m4 = c4 * (1.0 / 512.0);
            double sd = sqrt(m2);
            double den3 = m2 * sd;  if (den3 < 1e-4) den3 = 1e-4;
            double den4 = m2 * m2;  if (den4 < 1e-4) den4 = 1e-4;
            out[g * 35 + f]      = (float)mean;
            out[g * 35 + 14 + f] = (float)sd;
            out[g * 35 + 21 + f] = (float)(m3 / den3);
            out[g * 35 + 28 + f] = (float)(m4 / den4);
        }
    }
}

extern "C" void kernel_launch(void* const* d_in, const int* in_sizes, int n_in,
                              void* d_out, int out_size, void* d_ws, size_t ws_size,
                              hipStream_t stream) {
    const float* A = (const float*)d_in[0];   // [4096,4096] fp32, block-diagonal 0/1
    float* out = (float*)d_out;               // [8,35] fp32
    char* ws = (char*)d_ws;
    u64*   gmask = (u64*)(ws + OFF_MASK);
    float* gdeg  = (float*)(ws + OFF_DEG);
    float* f1g   = (float*)(ws + OFF_F1);
    float* featg = (float*)(ws + OFF_FEAT);

    k_pack <<<NNODE / 4, 256, 0, stream>>>(A, gmask, gdeg);
    k_pair <<<NG * 8,   256, 0, stream>>>(gmask, gdeg, featg, f1g);
    k_stats<<<NG,      1024, 0, stream>>>(gmask, gdeg, f1g, featg, out);
}

// Round 2
// 120.004 us; speedup vs baseline: 1.4505x; 1.4505x over previous
//
#include <hip/hip_runtime.h>
#include <stdint.h>

typedef unsigned long long u64;

#define NNODE 4096
#define NG    8
#define M     512      // nodes per graph
#define W     8        // 64-bit words per 512-bit mask

// workspace layout (bytes)
#define OFF_MASK 0                         // u64[4096][8]     = 262144 B
#define OFF_DEG  (262144)                  // float[4096]      =  16384 B
#define OFF_F1   (262144 + 16384)          // float[4096]      =  16384 B
#define OFF_FEAT (262144 + 32768)          // float[8][7][512] = 114688 B

// ---------------------------------------------------------------------------
// Kernel 1: pack diagonal-block adjacency rows into 512-bit masks + degrees.
// One wave per row; lane l covers columns [8l, 8l+8) of the block.
// ---------------------------------------------------------------------------
__global__ __launch_bounds__(256) void k_pack(const float* __restrict__ A,
                                              u64* __restrict__ gmask,
                                              float* __restrict__ gdeg) {
    int row  = (blockIdx.x << 2) + (threadIdx.x >> 6);  // 0..4095
    int lane = threadIdx.x & 63;
    int lo   = (row >> 9) << 9;                         // block column base
    const float* rowp = A + (size_t)row * NNODE + lo;
    float4 a = *(const float4*)(rowp + lane * 8);
    float4 b = *(const float4*)(rowp + lane * 8 + 4);
    unsigned int byte =
        (a.x != 0.f ? 1u : 0u) | (a.y != 0.f ? 2u : 0u) |
        (a.z != 0.f ? 4u : 0u) | (a.w != 0.f ? 8u : 0u) |
        (b.x != 0.f ? 16u : 0u) | (b.y != 0.f ? 32u : 0u) |
        (b.z != 0.f ? 64u : 0u) | (b.w != 0.f ? 128u : 0u);
    ((unsigned char*)gmask)[(size_t)row * 64 + lane] = (unsigned char)byte;
    int c = __popc(byte);
#pragma unroll
    for (int off = 32; off; off >>= 1) c += __shfl_down(c, off, 64);
    if (lane == 0) gdeg[row] = (float)c;
}

// ---------------------------------------------------------------------------
// Kernel 2: sparse ego-net features. Block = (graph g, half). Thread = node.
// f4 and reach via sparse iteration over ego1 bits (~deg+1 iters, not 512);
// f5 (M2@deg) and f2 (A@deg) via degree bit-planes + popcount.
// ---------------------------------------------------------------------------
__global__ __launch_bounds__(256) void k_feat(const u64* __restrict__ gmask,
                                              const float* __restrict__ gdeg,
                                              float* __restrict__ featg,
                                              float* __restrict__ f1g) {
    int g = blockIdx.x >> 1, half = blockIdx.x & 1;
    int t = threadIdx.x;
    __shared__ u64 smT[W * M];      // transposed [w][node], 32 KB
    __shared__ float sdeg[M];
    __shared__ u64 planes[9][W];    // degree bit-planes

    const u64* gm = gmask + (size_t)g * M * W;
    for (int idx = t; idx < M * W; idx += 256) {
        int u = idx >> 3, w = idx & 7;
        smT[w * M + u] = gm[idx];               // coalesced global read
    }
    for (int i = t; i < M; i += 256) sdeg[i] = gdeg[g * M + i];
    __syncthreads();

    int wv = t >> 6, lane = t & 63;
    for (int w = wv; w < W; w += 4) {           // wave wv builds words wv, wv+4
        int d = (int)sdeg[(w << 6) + lane];
#pragma unroll
        for (int k = 0; k < 9; k++) {
            u64 bal = __ballot(((d >> k) & 1) != 0);
            if (lane == 0) planes[k][w] = bal;
        }
    }
    __syncthreads();

    int n = half * 256 + t;
    u64 arow[W], m1[W], reach[W];
#pragma unroll
    for (int w = 0; w < W; w++) {
        arow[w] = smT[w * M + n];
        m1[w] = arow[w];
        reach[w] = 0ull;
    }
    m1[n >> 6] |= 1ull << (n & 63);             // M1 = A | I

    int f4 = 0;
    for (int w = 0; w < W; w++) {
        u64 bits = m1[w];
        while (bits) {                           // sparse: u in ego1(n)
            int b = __ffsll(bits) - 1;
            bits &= bits - 1;
            int u = (w << 6) + b;
#pragma unroll
            for (int w2 = 0; w2 < W; w2++) {
                u64 r = smT[w2 * M + u];
                reach[w2] |= r;                  // B>0 mask (A symmetric)
                f4 += __popcll(r & m1[w2]);      // edges ego1 -> ego1
            }
        }
    }
    int f6c = 0;
    u64 m2m[W];
#pragma unroll
    for (int w = 0; w < W; w++) { m2m[w] = m1[w] | reach[w]; f6c += __popcll(m2m[w]); }
    int f5i = 0, f2i = 0;
#pragma unroll
    for (int k = 0; k < 9; k++) {
        int c5 = 0, c2 = 0;
#pragma unroll
        for (int w = 0; w < W; w++) {
            c5 += __popcll(m2m[w] & planes[k][w]);   // M2 @ deg, bit-sliced
            c2 += __popcll(arow[w] & planes[k][w]);  // A  @ deg, bit-sliced
        }
        f5i += c5 << k;
        f2i += c2 << k;
    }
    float deg = sdeg[n];
    float f4raw = (float)f4;
    float f1 = (deg > 1.f) ? 2.f * (f4raw - deg) / (deg * (deg - 1.f)) : 0.f;
    float* fb = featg + (size_t)g * 7 * M;
    fb[0 * M + n] = deg;
    fb[1 * M + n] = f1;
    fb[2 * M + n] = (deg > 0.f) ? (float)f2i / deg : 0.f;
    fb[4 * M + n] = f4raw * 0.5f;
    fb[5 * M + n] = (float)f5i - 2.f * f4raw;
    fb[6 * M + n] = (float)f6c - deg - 1.f;
    f1g[g * M + n] = f1;
}

// ---------------------------------------------------------------------------
// Kernel 3: f3 = neighbor-mean of f1. Block per graph, thread per node.
// ---------------------------------------------------------------------------
__global__ __launch_bounds__(512) void k_f3(const u64* __restrict__ gmask,
                                            const float* __restrict__ gdeg,
                                            const float* __restrict__ f1g,
                                            float* __restrict__ featg) {
    int g = blockIdx.x;
    int t = threadIdx.x;
    __shared__ float f1s[M];
    f1s[t] = f1g[g * M + t];
    __syncthreads();

    const u64* m = gmask + ((size_t)g * M + t) * W;   // row-major, 64B/thread
    float sum = 0.f;
#pragma unroll
    for (int w = 0; w < W; w++) {
        u64 bits = m[w];                               // A row (no self bit)
        while (bits) {
            int b = __ffsll(bits) - 1;
            bits &= bits - 1;
            sum += f1s[(w << 6) + b];
        }
    }
    float deg = gdeg[g * M + t];
    featg[(size_t)g * 7 * M + 3 * M + t] = (deg > 0.f) ? sum / deg : 0.f;
}

// ---------------------------------------------------------------------------
// Kernel 4: per-(graph,feature) statistics. Block = (g, f, candidate-half).
// Median by rank-count with float4 LDS broadcast; moments in double (half 0).
// ---------------------------------------------------------------------------
__global__ __launch_bounds__(256) void k_stats(const float* __restrict__ featg,
                                               float* __restrict__ out) {
    int blk = blockIdx.x;            // 0..111
    int gf = blk >> 1, half = blk & 1;
    int g = gf / 7, f = gf % 7;
    int t = threadIdx.x;
    __shared__ __align__(16) float sv[M];
    __shared__ double rsum[4], r2[4], r3[4], r4[4];
    __shared__ double smean;

    sv[t]       = featg[(size_t)gf * M + t];
    sv[t + 256] = featg[(size_t)gf * M + t + 256];
    __syncthreads();

    int wv = t >> 6, lane = t & 63;
    if (half == 0) {                 // moments only once per (g,f)
        double s = (double)sv[t] + (double)sv[t + 256];
#pragma unroll
        for (int off = 32; off; off >>= 1) s += __shfl_xor(s, off, 64);
        if (lane == 0) rsum[wv] = s;
        __syncthreads();
        if (t == 0) smean = (rsum[0] + rsum[1] + rsum[2] + rsum[3]) * (1.0 / 512.0);
        __syncthreads();
        double mean = smean;
        double c1 = (double)sv[t] - mean, c2v = (double)sv[t + 256] - mean;
        double a2 = c1 * c1, b2 = c2v * c2v;
        double p2 = a2 + b2, p3 = a2 * c1 + b2 * c2v, p4 = a2 * a2 + b2 * b2;
#pragma unroll
        for (int off = 32; off; off >>= 1) {
            p2 += __shfl_xor(p2, off, 64);
            p3 += __shfl_xor(p3, off, 64);
            p4 += __shfl_xor(p4, off, 64);
        }
        if (lane == 0) { r2[wv] = p2; r3[wv] = p3; r4[wv] = p4; }
        __syncthreads();
        if (t == 0) {
            double m2 = (r2[0] + r2[1] + r2[2] + r2[3]) * (1.0 / 512.0);
            double m3 = (r3[0] + r3[1] + r3[2] + r3[3]) * (1.0 / 512.0);
            double m4 = (r4[0] + r4[1] + r4[2] + r4[3]) * (1.0 / 512.0);
            double sd = sqrt(m2);
            double den3 = m2 * sd;  if (den3 < 1e-4) den3 = 1e-4;
            double den4 = m2 * m2;  if (den4 < 1e-4) den4 = 1e-4;
            out[g * 35 + f]      = (float)smean;
            out[g * 35 + 14 + f] = (float)sd;
            out[g * 35 + 21 + f] = (float)(m3 / den3);
            out[g * 35 + 28 + f] = (float)(m4 / den4);
        }
    }

    // median: lower-middle element = rank 255 (torch.median semantics)
    float cv = sv[half * 256 + t];
    int less = 0, eq = 0;
    for (int j = 0; j < M; j += 4) {
        float4 x = *(const float4*)&sv[j];       // wave-uniform => broadcast
        less += (x.x < cv) + (x.y < cv) + (x.z < cv) + (x.w < cv);
        eq   += (x.x == cv) + (x.y == cv) + (x.z == cv) + (x.w == cv);
    }
    if (less <= 255 && less + eq > 255) out[g * 35 + 7 + f] = cv;
}

extern "C" void kernel_launch(void* const* d_in, const int* in_sizes, int n_in,
                              void* d_out, int out_size, void* d_ws, size_t ws_size,
                              hipStream_t stream) {
    const float* A = (const float*)d_in[0];   // [4096,4096] fp32, block-diagonal 0/1
    float* out = (float*)d_out;               // [8,35] fp32
    char* ws = (char*)d_ws;
    u64*   gmask = (u64*)(ws + OFF_MASK);
    float* gdeg  = (float*)(ws + OFF_DEG);
    float* f1g   = (float*)(ws + OFF_F1);
    float* featg = (float*)(ws + OFF_FEAT);

    k_pack <<<NNODE / 4, 256, 0, stream>>>(A, gmask, gdeg);
    k_feat <<<NG * 2,    256, 0, stream>>>(gmask, gdeg, featg, f1g);
    k_f3   <<<NG,        512, 0, stream>>>(gmask, gdeg, f1g, featg);
    k_stats<<<NG * 7 * 2, 256, 0, stream>>>(featg, out);
}